// Round 5
// baseline (218.185 us; speedup 1.0000x reference)
//
#include <hip/hip_runtime.h>

#define BATCH 16
#define SEQ   2048
#define EMB   1024
#define DH    128

typedef _Float16 half4_t __attribute__((ext_vector_type(4)));
typedef _Float16 half8_t __attribute__((ext_vector_type(8)));
typedef float    f32x4   __attribute__((ext_vector_type(4)));

// ---------------- workspace layout (bytes) ----------------
#define OFF_WT2 0u
#define OFF_QHI 0x200000u
#define OFF_QLO (OFF_QHI + 0x800000u)
#define OFF_KHI (OFF_QLO + 0x800000u)
#define OFF_KLO (OFF_KHI + 0x800000u)
#define OFF_VT  (OFF_KLO + 0x800000u)

// async global->LDS, 16B per lane (dst = wave-uniform base + lane*16)
__device__ __forceinline__ void gload16(const void* g, void* l) {
    __builtin_amdgcn_global_load_lds(
        (__attribute__((address_space(1))) const unsigned int*)g,
        (__attribute__((address_space(3))) unsigned int*)l, 16, 0, 0);
}

// ---------------- kernel 1: pack W into MFMA-fragment order ----------------
__global__ __launch_bounds__(256) void prep_w(
    const float* __restrict__ Wq, const float* __restrict__ Wk,
    const float* __restrict__ Wv, _Float16* __restrict__ Wt2) {
    const int t  = blockIdx.x * 256 + threadIdx.x;   // 0..81919
    const int kc = t / 2560, rem = t % 2560;
    const int lo = rem >= 1536 ? 1 : 0;
    const int rr = lo ? rem - 1536 : rem;
    const int nt = rr >> 6, c = rr & 63;             // c = g*16 + r
    const int g = c >> 4, r = c & 15;
    const int k0 = kc * 32 + g * 8;
    const float* W; int col;
    if (nt < 8)       { W = Wq; col = nt * 16 + r; }
    else if (nt < 16) { W = Wk; col = (nt - 8) * 16 + r; }
    else              { W = Wv; col = (nt - 16) * 16 + r; }
    half8_t v;
#pragma unroll
    for (int j = 0; j < 8; ++j) {
        float f = W[(size_t)(k0 + j) * DH + col];
        _Float16 h = (_Float16)f;
        v[j] = lo ? (_Float16)(f - (float)h) : h;
    }
    *(half8_t*)((char*)Wt2 + (size_t)kc * 40960 + (lo ? 24576 : 0)
                + (size_t)nt * 1024 + c * 16) = v;
}

// ---------------- kernel 2: QKV projection (pipelined, W in registers) ----------------
// Block: 4 waves, BM=64 rows, N=384. x double-buffered in LDS (2x8KB);
// W fragments loaded straight to VGPRs (packed layout -> coalesced 1KB/wave),
// double-buffered across kc with named register sets (static indexing).
__global__ __launch_bounds__(256) void proj_qkv(
    const float* __restrict__ x, const _Float16* __restrict__ Wt2,
    const float* __restrict__ bq, const float* __restrict__ bk,
    const float* __restrict__ bv,
    _Float16* __restrict__ qhi, _Float16* __restrict__ qlo,
    _Float16* __restrict__ khi, _Float16* __restrict__ klo,
    _Float16* __restrict__ vt) {
    __shared__ __align__(16) char lds[16384];
    const int tid = threadIdx.x, lane = tid & 63, w = tid >> 6;
    const int l15 = lane & 15, g = lane >> 4;
    const int m0  = blockIdx.x * 64;

    f32x4 acc[4][6];
#pragma unroll
    for (int mt = 0; mt < 4; ++mt)
#pragma unroll
        for (int j = 0; j < 6; ++j) acc[mt][j] = {};

    // stage x tile kc into LDS buffer buf (source-swizzled, linear dst)
    auto stage_x = [&](int kc, int buf) {
#pragma unroll
        for (int i = 0; i < 2; ++i) {
            const int c = w * 128 + i * 64 + lane;
            const int r = c >> 3;
            const int cc = (c & 7) ^ (r & 7);
            gload16(x + (size_t)(m0 + r) * EMB + kc * 32 + cc * 4,
                    lds + buf * 8192 + c * 16);
        }
    };

    // load this wave's 10 W fragments for kc into registers (coalesced)
    auto loadW = [&](int kc, half8_t (&wh)[6], half8_t (&wl)[4]) {
        const char* p = (const char*)Wt2 + (size_t)kc * 40960 + lane * 16;
#pragma unroll
        for (int j = 0; j < 6; ++j) {
            const int nt = (j >> 1) * 8 + (j & 1) * 4 + w;
            wh[j] = *(const half8_t*)(p + nt * 1024);
        }
#pragma unroll
        for (int j = 0; j < 4; ++j) {
            const int nt = (j >> 1) * 8 + (j & 1) * 4 + w;
            wl[j] = *(const half8_t*)(p + 24576 + nt * 1024);
        }
    };

    auto compute = [&](int buf, const half8_t (&wh)[6], const half8_t (&wl)[4]) {
        const char* xb = lds + buf * 8192;
        half8_t xh[4], xl[4];
#pragma unroll
        for (int mt = 0; mt < 4; ++mt) {
            const int row = mt * 16 + l15;
            const int sw = row & 7;
            f32x4 a0 = *(const f32x4*)(xb + row * 128 + (((g << 1))     ^ sw) * 16);
            f32x4 a1 = *(const f32x4*)(xb + row * 128 + (((g << 1) | 1) ^ sw) * 16);
#pragma unroll
            for (int j = 0; j < 4; ++j) {
                float f = a0[j]; _Float16 h = (_Float16)f;
                xh[mt][j] = h; xl[mt][j] = (_Float16)(f - (float)h);
                float f2 = a1[j]; _Float16 h2 = (_Float16)f2;
                xh[mt][j + 4] = h2; xl[mt][j + 4] = (_Float16)(f2 - (float)h2);
            }
        }
#pragma unroll
        for (int j = 0; j < 6; ++j) {
#pragma unroll
            for (int mt = 0; mt < 4; ++mt) {
                acc[mt][j] = __builtin_amdgcn_mfma_f32_16x16x32_f16(xh[mt], wh[j], acc[mt][j], 0, 0, 0);
                if (j < 4) {
                    acc[mt][j] = __builtin_amdgcn_mfma_f32_16x16x32_f16(xl[mt], wh[j], acc[mt][j], 0, 0, 0);
                    acc[mt][j] = __builtin_amdgcn_mfma_f32_16x16x32_f16(xh[mt], wl[j], acc[mt][j], 0, 0, 0);
                }
            }
        }
    };

    half8_t WhA[6], WhB[6];
    half8_t WlA[4], WlB[4];

    // prologue: tile 0 in flight
    stage_x(0, 0);
    loadW(0, WhA, WlA);

    // 2-phase pipeline, kc-pair unrolled for static cur/next register sets.
    // Barrier at top of each phase: (a) previous compute on the buffer being
    // restaged is done by ALL waves, (b) vmcnt(0) drain -> stage(kc) landed.
    for (int t2 = 0; t2 < 16; ++t2) {
        const int tA = 2 * t2;
        __syncthreads();
        stage_x(tA + 1, 1);                 // tA+1 <= 31 always
        loadW(tA + 1, WhB, WlB);
        compute(0, WhA, WlA);

        __syncthreads();
        if (tA + 2 < 32) {
            stage_x(tA + 2, 0);
            loadW(tA + 2, WhA, WlA);
        }
        compute(1, WhB, WlB);
    }

    // ---- epilogue ----
    const float SC = 46.166241308446828f;  // 32 * log2(e), folded into q
#pragma unroll
    for (int j = 0; j < 6; ++j) {
        const int nt = (j >> 1) * 8 + (j & 1) * 4 + w;
#pragma unroll
        for (int mt = 0; mt < 4; ++mt) {
            f32x4 a = acc[mt][j];
            if (j < 2) {                     // q
                const int n = nt * 16 + l15;
                const float bias = bq[n];
#pragma unroll
                for (int ri = 0; ri < 4; ++ri) {
                    const size_t m = m0 + mt * 16 + g * 4 + ri;
                    float qv = (a[ri] + bias) * SC;
                    _Float16 h = (_Float16)qv;
                    qhi[m * DH + n] = h;
                    qlo[m * DH + n] = (_Float16)(qv - (float)h);
                }
            } else if (j < 4) {              // k
                const int d = (nt - 8) * 16 + l15;
                const float bias = bk[d];
#pragma unroll
                for (int ri = 0; ri < 4; ++ri) {
                    const size_t m = m0 + mt * 16 + g * 4 + ri;
                    float kv = a[ri] + bias;
                    _Float16 h = (_Float16)kv;
                    khi[m * DH + d] = h;
                    klo[m * DH + d] = (_Float16)(kv - (float)h);
                }
            } else {                         // v (transposed store)
                const int d = (nt - 16) * 16 + l15;
                const float bias = bv[d];
                const int bb = m0 >> 11;
                const int s0 = (m0 & (SEQ - 1)) + mt * 16 + g * 4;
                half4_t vv;
#pragma unroll
                for (int ri = 0; ri < 4; ++ri) vv[ri] = (_Float16)(a[ri] + bias);
                *(half4_t*)(vt + (size_t)bb * DH * SEQ + (size_t)d * SEQ + s0) = vv;
            }
        }
    }
}

// ---------------- kernel 3: block-cooperative causal flash attention ----------------
// Block = 4 waves sharing one 64-row q-tile (wave w: rows q0+16w..+16).
// KV tiles of 32 staged in LDS (K hi 8KB | K lo 8KB | V^T 8KB), double-buffered.
// Pairing (j, 31-j) -> every block does exactly 66 kv-iterations. 256 blocks.
__global__ __launch_bounds__(256) void attn(
    const _Float16* __restrict__ qhi, const _Float16* __restrict__ qlo,
    const _Float16* __restrict__ khi, const _Float16* __restrict__ klo,
    const _Float16* __restrict__ vt, float* __restrict__ out) {
    __shared__ __align__(16) char lds[49152];
    const int tid = threadIdx.x, lane = tid & 63, w = tid >> 6;
    const int l15 = lane & 15, g = lane >> 4;
    const int gid = blockIdx.x;
    const int b   = ((gid & 7) << 1) | ((gid >> 3) & 1);  // 2 batches per XCD
    const int pr  = gid >> 4;                              // pair index 0..15

    const _Float16* kh_b = khi + (size_t)b * SEQ * DH;
    const _Float16* kl_b = klo + (size_t)b * SEQ * DH;
    const _Float16* v_b  = vt  + (size_t)b * DH * SEQ;

    auto stage = [&](int t, int buf) {
        const int kb = t * 32;
        char* dst = lds + buf * 24576;
#pragma unroll
        for (int i = 0; i < 2; ++i) {
            const int call = w * 2 + i;
            const int r  = call * 4 + (lane >> 4);
            const int cc = (lane & 15) ^ (r & 7);
            gload16(kh_b + (size_t)(kb + r) * DH + cc * 8, dst + call * 1024);
            gload16(kl_b + (size_t)(kb + r) * DH + cc * 8, dst + 8192 + call * 1024);
            const int dh = call * 16 + (lane >> 2);
            const int c2 = (lane & 3) ^ (dh & 3);
            gload16(v_b + (size_t)dh * SEQ + kb + c2 * 8, dst + 16384 + call * 1024);
        }
    };

    for (int pass = 0; pass < 2; ++pass) {
        const int jt  = pass ? 31 - pr : pr;
        const int q0  = jt * 64;
        const int qw0 = q0 + w * 16;
        const int nkv = 2 * (jt + 1);

        const size_t qrow = ((size_t)b * SEQ + qw0 + l15) * DH;
        half8_t Qh[4], Ql[4];
#pragma unroll
        for (int kk = 0; kk < 4; ++kk) {
            Qh[kk] = *(const half8_t*)(qhi + qrow + kk * 32 + g * 8);
            Ql[kk] = *(const half8_t*)(qlo + qrow + kk * 32 + g * 8);
        }

        f32x4 o[8];
#pragma unroll
        for (int dt = 0; dt < 8; ++dt) o[dt] = {};
        float mrun = -3.0e38f, ell = 0.0f;

        __syncthreads();
        stage(0, 0);

        for (int t = 0; t < nkv; ++t) {
            __syncthreads();
            if (t + 1 < nkv) stage(t + 1, (t + 1) & 1);

            const int kb = t * 32;
            if (kb <= qw0 + 15) {
                const char* kbuf = lds + (t & 1) * 24576;
                const int sw = l15 & 7;

                f32x4 sa0 = {}, sb0 = {}, sa1 = {}, sb1 = {};
#pragma unroll
                for (int kk = 0; kk < 4; ++kk) {
                    const int ch = ((kk * 4 + g) ^ sw) * 16;
                    half8_t kh0 = *(const half8_t*)(kbuf + l15 * 256 + ch);
                    half8_t kl0 = *(const half8_t*)(kbuf + 8192 + l15 * 256 + ch);
                    half8_t kh1 = *(const half8_t*)(kbuf + (16 + l15) * 256 + ch);
                    half8_t kl1 = *(const half8_t*)(kbuf + 8192 + (16 + l15) * 256 + ch);
                    sa0 = __builtin_amdgcn_mfma_f32_16x16x32_f16(kh0, Qh[kk], sa0, 0, 0, 0);
                    sb0 = __builtin_amdgcn_mfma_f32_16x16x32_f16(kl0, Qh[kk], sb0, 0, 0, 0);
                    sb0 = __builtin_amdgcn_mfma_f32_16x16x32_f16(kh0, Ql[kk], sb0, 0, 0, 0);
                    sa1 = __builtin_amdgcn_mfma_f32_16x16x32_f16(kh1, Qh[kk], sa1, 0, 0, 0);
                    sb1 = __builtin_amdgcn_mfma_f32_16x16x32_f16(kl1, Qh[kk], sb1, 0, 0, 0);
                    sb1 = __builtin_amdgcn_mfma_f32_16x16x32_f16(kh1, Ql[kk], sb1, 0, 0, 0);
                }
                f32x4 s0 = sa0 + sb0, s1 = sa1 + sb1;

                if (kb + 31 > qw0) {
#pragma unroll
                    for (int r = 0; r < 4; ++r) {
                        if (kb + g * 4 + r      > qw0 + l15) s0[r] = -3.0e38f;
                        if (kb + 16 + g * 4 + r > qw0 + l15) s1[r] = -3.0e38f;
                    }
                }

                float mt = fmaxf(fmaxf(fmaxf(s0[0], s0[1]), fmaxf(s0[2], s0[3])),
                                 fmaxf(fmaxf(s1[0], s1[1]), fmaxf(s1[2], s1[3])));
                mt = fmaxf(mt, __shfl_xor(mt, 16, 64));
                mt = fmaxf(mt, __shfl_xor(mt, 32, 64));
                if (!__all(mt <= mrun + 8.0f)) {   // defer-max (log2 units)
                    const float mnew = fmaxf(mrun, mt);
                    const float alpha = exp2f(mrun - mnew);
                    ell *= alpha;
#pragma unroll
                    for (int dt = 0; dt < 8; ++dt) o[dt] *= alpha;
                    mrun = mnew;
                }
                float p[8];
#pragma unroll
                for (int r = 0; r < 4; ++r) {
                    p[r]     = exp2f(s0[r] - mrun);
                    p[4 + r] = exp2f(s1[r] - mrun);
                }
                float ps = ((p[0] + p[1]) + (p[2] + p[3])) + ((p[4] + p[5]) + (p[6] + p[7]));
                ps += __shfl_xor(ps, 16, 64);
                ps += __shfl_xor(ps, 32, 64);
                ell += ps;

                half4_t pf0, pf1;
#pragma unroll
                for (int r = 0; r < 4; ++r) { pf0[r] = (_Float16)p[r]; pf1[r] = (_Float16)p[4 + r]; }

                const char* vbuf = kbuf + 16384;
                const int sw2 = l15 & 3;
                const int h8  = (g & 1) * 8;
                const int c0  = (((g >> 1))     ^ sw2) * 16 + h8;
                const int c1  = (((g >> 1) + 2) ^ sw2) * 16 + h8;
#pragma unroll
                for (int dt = 0; dt < 8; ++dt) {
                    const int rowb = (dt * 16 + l15) * 64;
                    half4_t v0 = *(const half4_t*)(vbuf + rowb + c0);
                    half4_t v1 = *(const half4_t*)(vbuf + rowb + c1);
                    o[dt] = __builtin_amdgcn_mfma_f32_16x16x16f16(v0, pf0, o[dt], 0, 0, 0);
                    o[dt] = __builtin_amdgcn_mfma_f32_16x16x16f16(v1, pf1, o[dt], 0, 0, 0);
                }
            }
        }

        const float rinv = 1.0f / ell;
        float* orow = out + ((size_t)b * SEQ + qw0 + l15) * DH + g * 4;
#pragma unroll
        for (int dt = 0; dt < 8; ++dt) {
            f32x4 ov = o[dt] * rinv;
            *(f32x4*)(orow + dt * 16) = ov;
        }
    }
}

extern "C" void kernel_launch(void* const* d_in, const int* in_sizes, int n_in,
                              void* d_out, int out_size, void* d_ws, size_t ws_size,
                              hipStream_t stream) {
    const float* x  = (const float*)d_in[0];
    const float* Wq = (const float*)d_in[1];
    const float* bq = (const float*)d_in[2];
    const float* Wk = (const float*)d_in[3];
    const float* bk = (const float*)d_in[4];
    const float* Wv = (const float*)d_in[5];
    const float* bv = (const float*)d_in[6];
    float* out = (float*)d_out;

    char* ws = (char*)d_ws;
    _Float16* Wt2  = (_Float16*)(ws + OFF_WT2);
    _Float16* q_hi = (_Float16*)(ws + OFF_QHI);
    _Float16* q_lo = (_Float16*)(ws + OFF_QLO);
    _Float16* k_hi = (_Float16*)(ws + OFF_KHI);
    _Float16* k_lo = (_Float16*)(ws + OFF_KLO);
    _Float16* v_t  = (_Float16*)(ws + OFF_VT);

    prep_w  <<<320, 256, 0, stream>>>(Wq, Wk, Wv, Wt2);
    proj_qkv<<<512, 256, 0, stream>>>(x, Wt2, bq, bk, bv, q_hi, q_lo, k_hi, k_lo, v_t);
    attn    <<<256, 256, 0, stream>>>(q_hi, q_lo, k_hi, k_lo, v_t, out);
}

// Round 6
// 211.733 us; speedup vs baseline: 1.0305x; 1.0305x over previous
//
#include <hip/hip_runtime.h>

#define BATCH 16
#define SEQ   2048
#define EMB   1024
#define DH    128

typedef _Float16 half4_t __attribute__((ext_vector_type(4)));
typedef _Float16 half8_t __attribute__((ext_vector_type(8)));
typedef float    f32x4   __attribute__((ext_vector_type(4)));

// ---------------- workspace layout (bytes) ----------------
// q/k hi+lo: fragment-packed [tile16tok][kk4][g4][l15 16][16B] = 4KB/tile, 8MB each
// v: packed  [stile32][half2][dt8][g4][l15 16][8B] = 8KB/stile, 8MB
#define OFF_WT2 0u
#define OFF_QHI 0x200000u
#define OFF_QLO (OFF_QHI + 0x800000u)
#define OFF_KHI (OFF_QLO + 0x800000u)
#define OFF_KLO (OFF_KHI + 0x800000u)
#define OFF_VT  (OFF_KLO + 0x800000u)

// async global->LDS, 16B per lane (dst = wave-uniform base + lane*16)
__device__ __forceinline__ void gload16(const void* g, void* l) {
    __builtin_amdgcn_global_load_lds(
        (__attribute__((address_space(1))) const unsigned int*)g,
        (__attribute__((address_space(3))) unsigned int*)l, 16, 0, 0);
}

// ---------------- kernel 1: pack W into MFMA-fragment order ----------------
__global__ __launch_bounds__(256) void prep_w(
    const float* __restrict__ Wq, const float* __restrict__ Wk,
    const float* __restrict__ Wv, _Float16* __restrict__ Wt2) {
    const int t  = blockIdx.x * 256 + threadIdx.x;   // 0..81919
    const int kc = t / 2560, rem = t % 2560;
    const int lo = rem >= 1536 ? 1 : 0;
    const int rr = lo ? rem - 1536 : rem;
    const int nt = rr >> 6, c = rr & 63;             // c = g*16 + r
    const int g = c >> 4, r = c & 15;
    const int k0 = kc * 32 + g * 8;
    const float* W; int col;
    if (nt < 8)       { W = Wq; col = nt * 16 + r; }
    else if (nt < 16) { W = Wk; col = (nt - 8) * 16 + r; }
    else              { W = Wv; col = (nt - 16) * 16 + r; }
    half8_t v;
#pragma unroll
    for (int j = 0; j < 8; ++j) {
        float f = W[(size_t)(k0 + j) * DH + col];
        _Float16 h = (_Float16)f;
        v[j] = lo ? (_Float16)(f - (float)h) : h;
    }
    *(half8_t*)((char*)Wt2 + (size_t)kc * 40960 + (lo ? 24576 : 0)
                + (size_t)nt * 1024 + c * 16) = v;
}

// ---------------- kernel 2: QKV projection ----------------
// 4 waves, BM=64, N=384, BK=64 per phase (16 phases).
// Phase: [barA] cvt-exchange (each wave converts ITS 16 rows -> f16 hi/lo frags
// in LDS, XOR-swizzled) [barB] stage x(t+1) + per-sub {loadW to regs, frag
// ds_reads, 56 MFMAs}. Epilogue: per-wave LDS transpose -> packed coalesced stores.
#define XBUF  0       // 2 x 16KB fp32 x tiles
#define FHI   32768   // 8KB f16 hi frags [64 rows][8 oct-slots][16B]
#define FLO   40960   // 8KB f16 lo frags

__global__ __launch_bounds__(256) void proj_qkv(
    const float* __restrict__ x, const _Float16* __restrict__ Wt2,
    const float* __restrict__ bq, const float* __restrict__ bk,
    const float* __restrict__ bv,
    char* __restrict__ qhi, char* __restrict__ qlo,
    char* __restrict__ khi, char* __restrict__ klo,
    char* __restrict__ vt) {
    __shared__ __align__(16) char lds[49152];
    const int tid = threadIdx.x, lane = tid & 63, w = tid >> 6;
    const int l15 = lane & 15, g = lane >> 4;
    const int m0  = blockIdx.x * 64;

    f32x4 acc[4][6];
#pragma unroll
    for (int mt = 0; mt < 4; ++mt)
#pragma unroll
        for (int j = 0; j < 6; ++j) acc[mt][j] = {};

    // stage x phase t (64 rows x 64 k fp32 = 16KB) into X[buf]; source-swizzled
    auto stage_x = [&](int t, int buf) {
#pragma unroll
        for (int i = 0; i < 4; ++i) {
            const int cb = w * 256 + i * 64;         // wave-uniform chunk base
            const int sidx = cb + lane;              // chunk slot 0..1023
            const int r = sidx >> 4, s = sidx & 15;
            const int c = s ^ (r & 7);               // global chunk (involution)
            gload16(x + (size_t)(m0 + r) * EMB + t * 64 + c * 4,
                    lds + XBUF + buf * 16384 + cb * 16);
        }
    };

    auto loadW = [&](int kc, half8_t (&wh)[6], half8_t (&wl)[4]) {
        const char* p = (const char*)Wt2 + (size_t)kc * 40960 + lane * 16;
#pragma unroll
        for (int j = 0; j < 6; ++j) {
            const int nt = (j >> 1) * 8 + (j & 1) * 4 + w;
            wh[j] = *(const half8_t*)(p + nt * 1024);
        }
#pragma unroll
        for (int j = 0; j < 4; ++j) {
            const int nt = (j >> 1) * 8 + (j & 1) * 4 + w;
            wl[j] = *(const half8_t*)(p + 24576 + nt * 1024);
        }
    };

    stage_x(0, 0);

#pragma unroll 2
    for (int t = 0; t < 16; ++t) {
        __syncthreads();   // barA: X[t&1] staged (vmcnt drained); frag reads of t-1 done

        // ---- cvt-exchange: this wave's 16 rows (R = w*16+l15), octets g*2, g*2+1
        {
            const char* Xb = lds + XBUF + (t & 1) * 16384;
            const int R = w * 16 + l15;
            const int rx = R & 7;
#pragma unroll
            for (int u = 0; u < 2; ++u) {
                const int o = g * 2 + u;             // octet 0..7
                f32x4 a0 = *(const f32x4*)(Xb + R * 256 + ((o * 2)     ^ rx) * 16);
                f32x4 a1 = *(const f32x4*)(Xb + R * 256 + ((o * 2 + 1) ^ rx) * 16);
                half8_t hi, lo;
#pragma unroll
                for (int jj = 0; jj < 4; ++jj) {
                    float f = a0[jj]; _Float16 h = (_Float16)f;
                    hi[jj] = h; lo[jj] = (_Float16)(f - (float)h);
                    float f2 = a1[jj]; _Float16 h2 = (_Float16)f2;
                    hi[jj + 4] = h2; lo[jj + 4] = (_Float16)(f2 - (float)h2);
                }
                *(half8_t*)(lds + FHI + R * 128 + (o ^ rx) * 16) = hi;
                *(half8_t*)(lds + FLO + R * 128 + (o ^ rx) * 16) = lo;
            }
        }
        __syncthreads();   // barB: frags ready; X[(t+1)&1] free

        if (t < 15) stage_x(t + 1, (t + 1) & 1);   // drained at next barA

#pragma unroll
        for (int s = 0; s < 2; ++s) {              // kc = 2t + s
            half8_t Wh[6], Wl[4];
            loadW(2 * t + s, Wh, Wl);
            half8_t xh[4], xl[4];
#pragma unroll
            for (int mt = 0; mt < 4; ++mt) {
                const int RR = mt * 16 + l15;
                const int sl = ((s * 4 + g) ^ (l15 & 7)) * 16;
                xh[mt] = *(const half8_t*)(lds + FHI + RR * 128 + sl);
                xl[mt] = *(const half8_t*)(lds + FLO + RR * 128 + sl);
            }
#pragma unroll
            for (int j = 0; j < 6; ++j) {
#pragma unroll
                for (int mt = 0; mt < 4; ++mt) {
                    acc[mt][j] = __builtin_amdgcn_mfma_f32_16x16x32_f16(xh[mt], Wh[j], acc[mt][j], 0, 0, 0);
                    if (j < 4) {
                        acc[mt][j] = __builtin_amdgcn_mfma_f32_16x16x32_f16(xl[mt], Wh[j], acc[mt][j], 0, 0, 0);
                        acc[mt][j] = __builtin_amdgcn_mfma_f32_16x16x32_f16(xh[mt], Wl[j], acc[mt][j], 0, 0, 0);
                    }
                }
            }
        }
    }

    // ---- epilogue: per-wave LDS 16x16 transpose -> packed coalesced stores ----
    __syncthreads();                                 // all frag reads done
    float* scr = (float*)(lds + FHI + w * 1280);     // 16 rows x 20 f32 (padded)
    const float SC = 46.166241308446828f;            // 32*log2(e) folded into q

#pragma unroll
    for (int j = 0; j < 6; ++j) {
        const int nt = (j >> 1) * 8 + (j & 1) * 4 + w;
        float bias;
        if (j < 2)      bias = bq[nt * 16 + l15];
        else if (j < 4) bias = bk[(nt - 8) * 16 + l15];
        else            bias = bv[(nt - 16) * 16 + l15];
#pragma unroll
        for (int mt = 0; mt < 4; ++mt) {
            f32x4 a = acc[mt][j];
#pragma unroll
            for (int r = 0; r < 4; ++r) {
                float v = a[r] + bias;
                if (j < 2) v *= SC;
                scr[(g * 4 + r) * 20 + l15] = v;     // [tok][dh], token=g*4+r, dh=l15
            }
            if (j < 4) {                             // ---- q,k: frag-packed store
                f32x4 tv = *(const f32x4*)(scr + l15 * 20 + g * 4);  // tok=l15, dh=g*4..+3
                half4_t h4, l4;
#pragma unroll
                for (int r = 0; r < 4; ++r) {
                    _Float16 h = (_Float16)tv[r];
                    h4[r] = h; l4[r] = (_Float16)(tv[r] - (float)h);
                }
                const int tIdx = m0 / 16 + mt;
                const int oct  = 2 * nt + (g >> 1);  // q: 0..15 ; k stores use oct-16
                const int octm = (j < 2) ? oct : oct - 16;
                const size_t off = (size_t)tIdx * 4096 + (octm >> 2) * 1024
                                 + (octm & 3) * 256 + l15 * 16 + (g & 1) * 8;
                char* dh_ = (j < 2) ? qhi : khi;
                char* dl_ = (j < 2) ? qlo : klo;
                *(half4_t*)(dh_ + off) = h4;
                *(half4_t*)(dl_ + off) = l4;
            } else {                                 // ---- v: packed [stile][h][dt][g][l15]
                half4_t v4;
#pragma unroll
                for (int r = 0; r < 4; ++r)
                    v4[r] = (_Float16)scr[(g * 4 + r) * 20 + l15];   // dh=l15, tok=g*4+r
                const int s0 = (m0 & (SEQ - 1)) + mt * 16;
                const int b  = m0 >> 11;
                const size_t off = ((size_t)b * 64 + (s0 >> 5)) * 8192
                                 + ((s0 >> 4) & 1) * 4096 + (nt - 16) * 512
                                 + g * 128 + l15 * 8;
                *(half4_t*)(vt + off) = v4;
            }
        }
    }
}

// ---------------- kernel 3: block-cooperative causal flash attention ----------------
// Same structure as round 5; staging is now pure linear copies from packed
// layouts, and all ds_reads are conflict-free fragment reads.
__global__ __launch_bounds__(256) void attn(
    const char* __restrict__ qhi, const char* __restrict__ qlo,
    const char* __restrict__ khi, const char* __restrict__ klo,
    const char* __restrict__ vt, float* __restrict__ out) {
    __shared__ __align__(16) char lds[49152];
    const int tid = threadIdx.x, lane = tid & 63, w = tid >> 6;
    const int l15 = lane & 15, g = lane >> 4;
    const int gid = blockIdx.x;
    const int b   = ((gid & 7) << 1) | ((gid >> 3) & 1);  // 2 batches per XCD
    const int pr  = gid >> 4;                              // pair index 0..15

    auto stage = [&](int t, int buf) {
        char* dst = lds + buf * 24576;
        const size_t kb4 = ((size_t)b * 128 + t * 2) * 4096;
        const size_t vb8 = ((size_t)b * 64 + t) * 8192;
#pragma unroll
        for (int i = 0; i < 2; ++i) {
            const int off = (w * 2 + i) * 1024;
            gload16(khi + kb4 + off + lane * 16, dst + off);
            gload16(klo + kb4 + off + lane * 16, dst + 8192 + off);
            gload16(vt  + vb8 + off + lane * 16, dst + 16384 + off);
        }
    };

    for (int pass = 0; pass < 2; ++pass) {
        const int jt  = pass ? 31 - pr : pr;
        const int qw0 = jt * 64 + w * 16;
        const int nkv = 2 * (jt + 1);

        const size_t qt4 = ((size_t)b * 128 + (qw0 >> 4)) * 4096;
        half8_t Qh[4], Ql[4];
#pragma unroll
        for (int kk = 0; kk < 4; ++kk) {
            const size_t o = qt4 + kk * 1024 + g * 256 + l15 * 16;
            Qh[kk] = *(const half8_t*)(qhi + o);
            Ql[kk] = *(const half8_t*)(qlo + o);
        }

        f32x4 o[8];
#pragma unroll
        for (int dt = 0; dt < 8; ++dt) o[dt] = {};
        float mrun = -3.0e38f, ell = 0.0f;

        __syncthreads();
        stage(0, 0);

        for (int t = 0; t < nkv; ++t) {
            __syncthreads();
            if (t + 1 < nkv) stage(t + 1, (t + 1) & 1);

            const int kb = t * 32;
            if (kb <= qw0 + 15) {
                const char* kbuf = lds + (t & 1) * 24576;

                f32x4 sa0 = {}, sb0 = {}, sa1 = {}, sb1 = {};
#pragma unroll
                for (int kk = 0; kk < 4; ++kk) {
                    const int fo = kk * 1024 + g * 256 + l15 * 16;
                    half8_t kh0 = *(const half8_t*)(kbuf + fo);
                    half8_t kl0 = *(const half8_t*)(kbuf + 8192 + fo);
                    half8_t kh1 = *(const half8_t*)(kbuf + 4096 + fo);
                    half8_t kl1 = *(const half8_t*)(kbuf + 12288 + fo);
                    sa0 = __builtin_amdgcn_mfma_f32_16x16x32_f16(kh0, Qh[kk], sa0, 0, 0, 0);
                    sb0 = __builtin_amdgcn_mfma_f32_16x16x32_f16(kl0, Qh[kk], sb0, 0, 0, 0);
                    sb0 = __builtin_amdgcn_mfma_f32_16x16x32_f16(kh0, Ql[kk], sb0, 0, 0, 0);
                    sa1 = __builtin_amdgcn_mfma_f32_16x16x32_f16(kh1, Qh[kk], sa1, 0, 0, 0);
                    sb1 = __builtin_amdgcn_mfma_f32_16x16x32_f16(kl1, Qh[kk], sb1, 0, 0, 0);
                    sb1 = __builtin_amdgcn_mfma_f32_16x16x32_f16(kh1, Ql[kk], sb1, 0, 0, 0);
                }
                f32x4 s0 = sa0 + sb0, s1 = sa1 + sb1;

                if (kb + 31 > qw0) {
#pragma unroll
                    for (int r = 0; r < 4; ++r) {
                        if (kb + g * 4 + r      > qw0 + l15) s0[r] = -3.0e38f;
                        if (kb + 16 + g * 4 + r > qw0 + l15) s1[r] = -3.0e38f;
                    }
                }

                float mt = fmaxf(fmaxf(fmaxf(s0[0], s0[1]), fmaxf(s0[2], s0[3])),
                                 fmaxf(fmaxf(s1[0], s1[1]), fmaxf(s1[2], s1[3])));
                mt = fmaxf(mt, __shfl_xor(mt, 16, 64));
                mt = fmaxf(mt, __shfl_xor(mt, 32, 64));
                if (!__all(mt <= mrun + 8.0f)) {   // defer-max (log2 units)
                    const float mnew = fmaxf(mrun, mt);
                    const float alpha = exp2f(mrun - mnew);
                    ell *= alpha;
#pragma unroll
                    for (int dt = 0; dt < 8; ++dt) o[dt] *= alpha;
                    mrun = mnew;
                }
                float p[8];
#pragma unroll
                for (int r = 0; r < 4; ++r) {
                    p[r]     = exp2f(s0[r] - mrun);
                    p[4 + r] = exp2f(s1[r] - mrun);
                }
                float ps = ((p[0] + p[1]) + (p[2] + p[3])) + ((p[4] + p[5]) + (p[6] + p[7]));
                ps += __shfl_xor(ps, 16, 64);
                ps += __shfl_xor(ps, 32, 64);
                ell += ps;

                half4_t pf0, pf1;
#pragma unroll
                for (int r = 0; r < 4; ++r) { pf0[r] = (_Float16)p[r]; pf1[r] = (_Float16)p[4 + r]; }

                const char* vbuf = kbuf + 16384;
#pragma unroll
                for (int dt = 0; dt < 8; ++dt) {
                    const int vo = dt * 512 + g * 128 + l15 * 8;
                    half4_t v0 = *(const half4_t*)(vbuf + vo);
                    half4_t v1 = *(const half4_t*)(vbuf + 4096 + vo);
                    o[dt] = __builtin_amdgcn_mfma_f32_16x16x16f16(v0, pf0, o[dt], 0, 0, 0);
                    o[dt] = __builtin_amdgcn_mfma_f32_16x16x16f16(v1, pf1, o[dt], 0, 0, 0);
                }
            }
        }

        const float rinv = 1.0f / ell;
        float* orow = out + ((size_t)b * SEQ + qw0 + l15) * DH + g * 4;
#pragma unroll
        for (int dt = 0; dt < 8; ++dt) {
            f32x4 ov = o[dt] * rinv;
            *(f32x4*)(orow + dt * 16) = ov;
        }
    }
}

extern "C" void kernel_launch(void* const* d_in, const int* in_sizes, int n_in,
                              void* d_out, int out_size, void* d_ws, size_t ws_size,
                              hipStream_t stream) {
    const float* x  = (const float*)d_in[0];
    const float* Wq = (const float*)d_in[1];
    const float* bq = (const float*)d_in[2];
    const float* Wk = (const float*)d_in[3];
    const float* bk = (const float*)d_in[4];
    const float* Wv = (const float*)d_in[5];
    const float* bv = (const float*)d_in[6];
    float* out = (float*)d_out;

    char* ws = (char*)d_ws;
    _Float16* Wt2 = (_Float16*)(ws + OFF_WT2);
    char* q_hi = ws + OFF_QHI;
    char* q_lo = ws + OFF_QLO;
    char* k_hi = ws + OFF_KHI;
    char* k_lo = ws + OFF_KLO;
    char* v_t  = ws + OFF_VT;

    prep_w  <<<320, 256, 0, stream>>>(Wq, Wk, Wv, Wt2);
    proj_qkv<<<512, 256, 0, stream>>>(x, Wt2, bq, bk, bv, q_hi, q_lo, k_hi, k_lo, v_t);
    attn    <<<256, 256, 0, stream>>>(q_hi, q_lo, k_hi, k_lo, v_t, out);
}

// Round 7
// 168.247 us; speedup vs baseline: 1.2968x; 1.2585x over previous
//
#include <hip/hip_runtime.h>

#define BATCH 16
#define SEQ   2048
#define EMB   1024
#define DH    128

typedef _Float16 half4_t __attribute__((ext_vector_type(4)));
typedef _Float16 half8_t __attribute__((ext_vector_type(8)));
typedef float    f32x4   __attribute__((ext_vector_type(4)));

// ---------------- workspace layout (bytes) ----------------
// q/k hi+lo: fragment-packed [tile16tok][kk4][g4][l15 16][16B] = 4KB/tile, 8MB each
// v: packed  [stile32][half2][dt8][g4][l15 16][8B] = 8KB/stile, 8MB
#define OFF_WT2 0u
#define OFF_QHI 0x200000u
#define OFF_QLO (OFF_QHI + 0x800000u)
#define OFF_KHI (OFF_QLO + 0x800000u)
#define OFF_KLO (OFF_KHI + 0x800000u)
#define OFF_VT  (OFF_KLO + 0x800000u)

// async global->LDS, 16B per lane (dst = wave-uniform base + lane*16)
__device__ __forceinline__ void gload16(const void* g, void* l) {
    __builtin_amdgcn_global_load_lds(
        (__attribute__((address_space(1))) const unsigned int*)g,
        (__attribute__((address_space(3))) unsigned int*)l, 16, 0, 0);
}

// ---------------- kernel 1: pack W into MFMA-fragment order ----------------
__global__ __launch_bounds__(256) void prep_w(
    const float* __restrict__ Wq, const float* __restrict__ Wk,
    const float* __restrict__ Wv, _Float16* __restrict__ Wt2) {
    const int t  = blockIdx.x * 256 + threadIdx.x;   // 0..81919
    const int kc = t / 2560, rem = t % 2560;
    const int lo = rem >= 1536 ? 1 : 0;
    const int rr = lo ? rem - 1536 : rem;
    const int nt = rr >> 6, c = rr & 63;             // c = g*16 + r
    const int g = c >> 4, r = c & 15;
    const int k0 = kc * 32 + g * 8;
    const float* W; int col;
    if (nt < 8)       { W = Wq; col = nt * 16 + r; }
    else if (nt < 16) { W = Wk; col = (nt - 8) * 16 + r; }
    else              { W = Wv; col = (nt - 16) * 16 + r; }
    half8_t v;
#pragma unroll
    for (int j = 0; j < 8; ++j) {
        float f = W[(size_t)(k0 + j) * DH + col];
        _Float16 h = (_Float16)f;
        v[j] = lo ? (_Float16)(f - (float)h) : h;
    }
    *(half8_t*)((char*)Wt2 + (size_t)kc * 40960 + (lo ? 24576 : 0)
                + (size_t)nt * 1024 + c * 16) = v;
}

// ---------------- kernel 2: QKV projection ----------------
// BM=32, 4 waves, grid 1024 (4 blocks/CU): many independent barrier domains
// keep HBM requests in flight continuously. Per phase (BK=64): [barA] cvt-
// exchange (1 octet/lane) [barB] stage x(t+1) + 2x{loadW->regs, frag reads,
// 28 MFMA/wave}. Layouts identical to round 6.
#define XBUF  0       // 2 x 8KB fp32 x tiles (32 rows x 64 k)
#define FHI   16384   // 4KB f16 hi frags [32 rows][8 oct-slots][16B]
#define FLO   20480   // 4KB f16 lo frags

__global__ __launch_bounds__(256, 4) void proj_qkv(
    const float* __restrict__ x, const _Float16* __restrict__ Wt2,
    const float* __restrict__ bq, const float* __restrict__ bk,
    const float* __restrict__ bv,
    char* __restrict__ qhi, char* __restrict__ qlo,
    char* __restrict__ khi, char* __restrict__ klo,
    char* __restrict__ vt) {
    __shared__ __align__(16) char lds[24576];
    const int tid = threadIdx.x, lane = tid & 63, w = tid >> 6;
    const int l15 = lane & 15, g = lane >> 4;
    const int m0  = blockIdx.x * 32;

    f32x4 acc[2][6];
#pragma unroll
    for (int mt = 0; mt < 2; ++mt)
#pragma unroll
        for (int j = 0; j < 6; ++j) acc[mt][j] = {};

    // stage x phase t (32 rows x 64 k fp32 = 8KB) into X[buf]; source-swizzled
    auto stage_x = [&](int t, int buf) {
#pragma unroll
        for (int i = 0; i < 2; ++i) {
            const int cb = w * 128 + i * 64;         // wave-uniform chunk base
            const int sidx = cb + lane;              // chunk slot 0..511
            const int r = sidx >> 4, s = sidx & 15;
            const int c = s ^ (r & 7);               // global chunk (involution)
            gload16(x + (size_t)(m0 + r) * EMB + t * 64 + c * 4,
                    lds + XBUF + buf * 8192 + cb * 16);
        }
    };

    auto loadW = [&](int kc, half8_t (&wh)[6], half8_t (&wl)[4]) {
        const char* p = (const char*)Wt2 + (size_t)kc * 40960 + lane * 16;
#pragma unroll
        for (int j = 0; j < 6; ++j) {
            const int nt = (j >> 1) * 8 + (j & 1) * 4 + w;
            wh[j] = *(const half8_t*)(p + nt * 1024);
        }
#pragma unroll
        for (int j = 0; j < 4; ++j) {
            const int nt = (j >> 1) * 8 + (j & 1) * 4 + w;
            wl[j] = *(const half8_t*)(p + 24576 + nt * 1024);
        }
    };

    stage_x(0, 0);

    for (int t = 0; t < 16; ++t) {
        __syncthreads();   // barA: X[t&1] staged (vmcnt drained); frag reads of t-1 done

        // ---- cvt-exchange: 1 octet/lane. Row R = w*8 + (lane>>3), octet o = lane&7.
        {
            const char* Xb = lds + XBUF + (t & 1) * 8192;
            const int R = w * 8 + (lane >> 3);
            const int o = lane & 7;
            const int rx = R & 7;
            f32x4 a0 = *(const f32x4*)(Xb + R * 256 + ((o * 2)     ^ rx) * 16);
            f32x4 a1 = *(const f32x4*)(Xb + R * 256 + ((o * 2 + 1) ^ rx) * 16);
            half8_t hi, lo;
#pragma unroll
            for (int jj = 0; jj < 4; ++jj) {
                float f = a0[jj]; _Float16 h = (_Float16)f;
                hi[jj] = h; lo[jj] = (_Float16)(f - (float)h);
                float f2 = a1[jj]; _Float16 h2 = (_Float16)f2;
                hi[jj + 4] = h2; lo[jj + 4] = (_Float16)(f2 - (float)h2);
            }
            *(half8_t*)(lds + FHI + R * 128 + (o ^ rx) * 16) = hi;
            *(half8_t*)(lds + FLO + R * 128 + (o ^ rx) * 16) = lo;
        }
        __syncthreads();   // barB: frags ready; X[(t+1)&1] free

        if (t < 15) stage_x(t + 1, (t + 1) & 1);   // drained at next barA

#pragma unroll
        for (int s = 0; s < 2; ++s) {              // kc = 2t + s
            half8_t Wh[6], Wl[4];
            loadW(2 * t + s, Wh, Wl);
            half8_t xh[2], xl[2];
#pragma unroll
            for (int mt = 0; mt < 2; ++mt) {
                const int RR = mt * 16 + l15;
                const int sl = ((s * 4 + g) ^ (l15 & 7)) * 16;
                xh[mt] = *(const half8_t*)(lds + FHI + RR * 128 + sl);
                xl[mt] = *(const half8_t*)(lds + FLO + RR * 128 + sl);
            }
#pragma unroll
            for (int j = 0; j < 6; ++j) {
#pragma unroll
                for (int mt = 0; mt < 2; ++mt) {
                    acc[mt][j] = __builtin_amdgcn_mfma_f32_16x16x32_f16(xh[mt], Wh[j], acc[mt][j], 0, 0, 0);
                    if (j < 4) {
                        acc[mt][j] = __builtin_amdgcn_mfma_f32_16x16x32_f16(xl[mt], Wh[j], acc[mt][j], 0, 0, 0);
                        acc[mt][j] = __builtin_amdgcn_mfma_f32_16x16x32_f16(xh[mt], Wl[j], acc[mt][j], 0, 0, 0);
                    }
                }
            }
        }
    }

    // ---- epilogue: per-wave LDS 16x16 transpose -> packed coalesced stores ----
    __syncthreads();                                 // all frag reads done
    float* scr = (float*)(lds + FHI + w * 1280);     // 16 rows x 20 f32 (padded)
    const float SC = 46.166241308446828f;            // 32*log2(e) folded into q

#pragma unroll
    for (int j = 0; j < 6; ++j) {
        const int nt = (j >> 1) * 8 + (j & 1) * 4 + w;
        float bias;
        if (j < 2)      bias = bq[nt * 16 + l15];
        else if (j < 4) bias = bk[(nt - 8) * 16 + l15];
        else            bias = bv[(nt - 16) * 16 + l15];
#pragma unroll
        for (int mt = 0; mt < 2; ++mt) {
            f32x4 a = acc[mt][j];
#pragma unroll
            for (int r = 0; r < 4; ++r) {
                float v = a[r] + bias;
                if (j < 2) v *= SC;
                scr[(g * 4 + r) * 20 + l15] = v;     // [tok][dh], token=g*4+r, dh=l15
            }
            if (j < 4) {                             // ---- q,k: frag-packed store
                f32x4 tv = *(const f32x4*)(scr + l15 * 20 + g * 4);  // tok=l15, dh=g*4..+3
                half4_t h4, l4;
#pragma unroll
                for (int r = 0; r < 4; ++r) {
                    _Float16 h = (_Float16)tv[r];
                    h4[r] = h; l4[r] = (_Float16)(tv[r] - (float)h);
                }
                const int tIdx = m0 / 16 + mt;
                const int oct  = 2 * nt + (g >> 1);  // q: 0..15 ; k stores use oct-16
                const int octm = (j < 2) ? oct : oct - 16;
                const size_t off = (size_t)tIdx * 4096 + (octm >> 2) * 1024
                                 + (octm & 3) * 256 + l15 * 16 + (g & 1) * 8;
                char* dh_ = (j < 2) ? qhi : khi;
                char* dl_ = (j < 2) ? qlo : klo;
                *(half4_t*)(dh_ + off) = h4;
                *(half4_t*)(dl_ + off) = l4;
            } else {                                 // ---- v: packed [stile][h][dt][g][l15]
                half4_t v4;
#pragma unroll
                for (int r = 0; r < 4; ++r)
                    v4[r] = (_Float16)scr[(g * 4 + r) * 20 + l15];   // dh=l15, tok=g*4+r
                const int s0 = (m0 & (SEQ - 1)) + mt * 16;
                const int b  = m0 >> 11;
                const size_t off = ((size_t)b * 64 + (s0 >> 5)) * 8192
                                 + ((s0 >> 4) & 1) * 4096 + (nt - 16) * 512
                                 + g * 128 + l15 * 8;
                *(half4_t*)(vt + off) = v4;
            }
        }
    }
}

// ---------------- kernel 3: block-cooperative causal flash attention ----------------
__global__ __launch_bounds__(256) void attn(
    const char* __restrict__ qhi, const char* __restrict__ qlo,
    const char* __restrict__ khi, const char* __restrict__ klo,
    const char* __restrict__ vt, float* __restrict__ out) {
    __shared__ __align__(16) char lds[49152];
    const int tid = threadIdx.x, lane = tid & 63, w = tid >> 6;
    const int l15 = lane & 15, g = lane >> 4;
    const int gid = blockIdx.x;
    const int b   = ((gid & 7) << 1) | ((gid >> 3) & 1);  // 2 batches per XCD
    const int pr  = gid >> 4;                              // pair index 0..15

    auto stage = [&](int t, int buf) {
        char* dst = lds + buf * 24576;
        const size_t kb4 = ((size_t)b * 128 + t * 2) * 4096;
        const size_t vb8 = ((size_t)b * 64 + t) * 8192;
#pragma unroll
        for (int i = 0; i < 2; ++i) {
            const int off = (w * 2 + i) * 1024;
            gload16(khi + kb4 + off + lane * 16, dst + off);
            gload16(klo + kb4 + off + lane * 16, dst + 8192 + off);
            gload16(vt  + vb8 + off + lane * 16, dst + 16384 + off);
        }
    };

    for (int pass = 0; pass < 2; ++pass) {
        const int jt  = pass ? 31 - pr : pr;
        const int qw0 = jt * 64 + w * 16;
        const int nkv = 2 * (jt + 1);

        const size_t qt4 = ((size_t)b * 128 + (qw0 >> 4)) * 4096;
        half8_t Qh[4], Ql[4];
#pragma unroll
        for (int kk = 0; kk < 4; ++kk) {
            const size_t o = qt4 + kk * 1024 + g * 256 + l15 * 16;
            Qh[kk] = *(const half8_t*)(qhi + o);
            Ql[kk] = *(const half8_t*)(qlo + o);
        }

        f32x4 o[8];
#pragma unroll
        for (int dt = 0; dt < 8; ++dt) o[dt] = {};
        float mrun = -3.0e38f, ell = 0.0f;

        __syncthreads();
        stage(0, 0);

        for (int t = 0; t < nkv; ++t) {
            __syncthreads();
            if (t + 1 < nkv) stage(t + 1, (t + 1) & 1);

            const int kb = t * 32;
            if (kb <= qw0 + 15) {
                const char* kbuf = lds + (t & 1) * 24576;

                f32x4 sa0 = {}, sb0 = {}, sa1 = {}, sb1 = {};
#pragma unroll
                for (int kk = 0; kk < 4; ++kk) {
                    const int fo = kk * 1024 + g * 256 + l15 * 16;
                    half8_t kh0 = *(const half8_t*)(kbuf + fo);
                    half8_t kl0 = *(const half8_t*)(kbuf + 8192 + fo);
                    half8_t kh1 = *(const half8_t*)(kbuf + 4096 + fo);
                    half8_t kl1 = *(const half8_t*)(kbuf + 12288 + fo);
                    sa0 = __builtin_amdgcn_mfma_f32_16x16x32_f16(kh0, Qh[kk], sa0, 0, 0, 0);
                    sb0 = __builtin_amdgcn_mfma_f32_16x16x32_f16(kl0, Qh[kk], sb0, 0, 0, 0);
                    sb0 = __builtin_amdgcn_mfma_f32_16x16x32_f16(kh0, Ql[kk], sb0, 0, 0, 0);
                    sa1 = __builtin_amdgcn_mfma_f32_16x16x32_f16(kh1, Qh[kk], sa1, 0, 0, 0);
                    sb1 = __builtin_amdgcn_mfma_f32_16x16x32_f16(kl1, Qh[kk], sb1, 0, 0, 0);
                    sb1 = __builtin_amdgcn_mfma_f32_16x16x32_f16(kh1, Ql[kk], sb1, 0, 0, 0);
                }
                f32x4 s0 = sa0 + sb0, s1 = sa1 + sb1;

                if (kb + 31 > qw0) {
#pragma unroll
                    for (int r = 0; r < 4; ++r) {
                        if (kb + g * 4 + r      > qw0 + l15) s0[r] = -3.0e38f;
                        if (kb + 16 + g * 4 + r > qw0 + l15) s1[r] = -3.0e38f;
                    }
                }

                float mt = fmaxf(fmaxf(fmaxf(s0[0], s0[1]), fmaxf(s0[2], s0[3])),
                                 fmaxf(fmaxf(s1[0], s1[1]), fmaxf(s1[2], s1[3])));
                mt = fmaxf(mt, __shfl_xor(mt, 16, 64));
                mt = fmaxf(mt, __shfl_xor(mt, 32, 64));
                if (!__all(mt <= mrun + 8.0f)) {   // defer-max (log2 units)
                    const float mnew = fmaxf(mrun, mt);
                    const float alpha = exp2f(mrun - mnew);
                    ell *= alpha;
#pragma unroll
                    for (int dt = 0; dt < 8; ++dt) o[dt] *= alpha;
                    mrun = mnew;
                }
                float p[8];
#pragma unroll
                for (int r = 0; r < 4; ++r) {
                    p[r]     = exp2f(s0[r] - mrun);
                    p[4 + r] = exp2f(s1[r] - mrun);
                }
                float ps = ((p[0] + p[1]) + (p[2] + p[3])) + ((p[4] + p[5]) + (p[6] + p[7]));
                ps += __shfl_xor(ps, 16, 64);
                ps += __shfl_xor(ps, 32, 64);
                ell += ps;

                half4_t pf0, pf1;
#pragma unroll
                for (int r = 0; r < 4; ++r) { pf0[r] = (_Float16)p[r]; pf1[r] = (_Float16)p[4 + r]; }

                const char* vbuf = kbuf + 16384;
#pragma unroll
                for (int dt = 0; dt < 8; ++dt) {
                    const int vo = dt * 512 + g * 128 + l15 * 8;
                    half4_t v0 = *(const half4_t*)(vbuf + vo);
                    half4_t v1 = *(const half4_t*)(vbuf + 4096 + vo);
                    o[dt] = __builtin_amdgcn_mfma_f32_16x16x16f16(v0, pf0, o[dt], 0, 0, 0);
                    o[dt] = __builtin_amdgcn_mfma_f32_16x16x16f16(v1, pf1, o[dt], 0, 0, 0);
                }
            }
        }

        const float rinv = 1.0f / ell;
        float* orow = out + ((size_t)b * SEQ + qw0 + l15) * DH + g * 4;
#pragma unroll
        for (int dt = 0; dt < 8; ++dt) {
            f32x4 ov = o[dt] * rinv;
            *(f32x4*)(orow + dt * 16) = ov;
        }
    }
}

extern "C" void kernel_launch(void* const* d_in, const int* in_sizes, int n_in,
                              void* d_out, int out_size, void* d_ws, size_t ws_size,
                              hipStream_t stream) {
    const float* x  = (const float*)d_in[0];
    const float* Wq = (const float*)d_in[1];
    const float* bq = (const float*)d_in[2];
    const float* Wk = (const float*)d_in[3];
    const float* bk = (const float*)d_in[4];
    const float* Wv = (const float*)d_in[5];
    const float* bv = (const float*)d_in[6];
    float* out = (float*)d_out;

    char* ws = (char*)d_ws;
    _Float16* Wt2 = (_Float16*)(ws + OFF_WT2);
    char* q_hi = ws + OFF_QHI;
    char* q_lo = ws + OFF_QLO;
    char* k_hi = ws + OFF_KHI;
    char* k_lo = ws + OFF_KLO;
    char* v_t  = ws + OFF_VT;

    prep_w  <<<320, 256, 0, stream>>>(Wq, Wk, Wv, Wt2);
    proj_qkv<<<1024, 256, 0, stream>>>(x, Wt2, bq, bk, bv, q_hi, q_lo, k_hi, k_lo, v_t);
    attn    <<<256, 256, 0, stream>>>(q_hi, q_lo, k_hi, k_lo, v_t, out);
}